// Round 11
// baseline (542.655 us; speedup 1.0000x reference)
//
#include <hip/hip_runtime.h>
#include <hip/hip_bf16.h>
#include <math.h>

#define NODE_DIM  64
#define EDGE_DIM  32
#define NUM_GAUSS 16
#define HIDDEN    128
#define CAT_DIM   160
#define TBL_BINS  2048
#define TBL_SCALE 256.0f                // bins per unit distance (domain [0,8))
#define L1ABSZ    (64 * 256)            // packed W1ab per layer (K=64, N=256)
#define L2SZ      (HIDDEN * NODE_DIM)   // packed W2 per layer   (K=128, N=64)
#define TBLSZ     (2 * TBL_BINS * 128)  // per-layer edge-attr table entries

// Pre-scale: pa/pb/tbl carry value * -log2(e); gather uses exp2 directly and
// un-scales the accumulated sum by -ln(2) once per node.
#define NEG_L2E   (-1.442695040888963f)
#define NEG_LN2   (-0.6931471805599453f)

// CSR build buckets: 512 nodes per bucket, max 1024 buckets (N <= 524288)
#define BKT_SH    9
#define BKT_SZ    512
#define NBKT_MAX  1024

// Column-permuted storage: idx64(c)=(c&15)*4+(c>>4)  (64-wide: hb, ht)
//                          idx128(c)=(c&15)*8+(c>>4) (128-wide: pa, pb, tbl, Sb)
// Weights' K dims are packed with the same permutation, so all GEMMs are invariant.
// Edge record: rec = (src << 12) | ety   (src<2^20, ety<2^12) — single 4 B scatter.
// h is carried in bf16 only (hb).
// pa AND pb (the gathered message halves) are stored FP8 e4m3 (128 B rows) to halve
// the gather-path traffic; tbl and Sb stay bf16.
// Fusions: node-embed init lives in the first k_node; graph mean-pool lives in the
// last k_node (reads its own LDS ht tile; hb store skipped there).

typedef __attribute__((ext_vector_type(8))) short short8;
typedef __attribute__((ext_vector_type(4))) short short4v;
typedef __attribute__((ext_vector_type(4))) float float4v;
typedef __attribute__((ext_vector_type(2))) float floatx2;

static __device__ __forceinline__ short f2bf(float x) {
  __hip_bfloat16 h = __float2bfloat16(x);
  return *reinterpret_cast<short*>(&h);
}
static __device__ __forceinline__ float bf2f(short s) {
  return __uint_as_float(((unsigned)(unsigned short)s) << 16);
}
static __device__ __forceinline__ float bflo(unsigned u) { return __uint_as_float(u << 16); }
static __device__ __forceinline__ float bfhi(unsigned u) { return __uint_as_float(u & 0xffff0000u); }

#if defined(__has_builtin) && __has_builtin(__builtin_amdgcn_exp2f)
static __device__ __forceinline__ float hw_exp2(float x) { return __builtin_amdgcn_exp2f(x); }
#else
static __device__ __forceinline__ float hw_exp2(float x) { return exp2f(x); }
#endif

__global__ void k_zero_f(float* __restrict__ p, int n) {
  int stride = gridDim.x * blockDim.x;
  for (int i = blockIdx.x * blockDim.x + threadIdx.x; i < n; i += stride) p[i] = 0.f;
}
__global__ void k_zero_i(int* __restrict__ p, int n) {
  int i = blockIdx.x * blockDim.x + threadIdx.x;
  if (i < n) p[i] = 0;
}

// ---------------- edge precompute: rec = (src<<12)|(kind<<11)|bin; LDS bucket histogram ----------------
__global__ __launch_bounds__(256) void k_edge_pre(
    const int* __restrict__ src, const int* __restrict__ dst,
    const float* __restrict__ coords, const int* __restrict__ isr,
    int* __restrict__ rec, int* __restrict__ bkt_total, int E) {
  __shared__ int h[NBKT_MAX];
  for (int i = threadIdx.x; i < NBKT_MAX; i += 256) h[i] = 0;
  __syncthreads();
  int stride = gridDim.x * blockDim.x;
  for (int e = blockIdx.x * blockDim.x + threadIdx.x; e < E; e += stride) {
    int s = src[e], d = dst[e];
    float dx = coords[s*3+0] - coords[d*3+0];
    float dy = coords[s*3+1] - coords[d*3+1];
    float dz = coords[s*3+2] - coords[d*3+2];
    float dist = sqrtf(dx*dx + dy*dy + dz*dz);
    int bin = (int)(dist * TBL_SCALE);
    bin = (bin > TBL_BINS - 1) ? TBL_BINS - 1 : bin;
    int kind = (isr[s] != isr[d]) ? 1 : 0;
    rec[e] = (s << 12) | (kind << 11) | bin;
    atomicAdd(&h[d >> BKT_SH], 1);
  }
  __syncthreads();
  for (int i = threadIdx.x; i < NBKT_MAX; i += 256)
    if (h[i]) atomicAdd(&bkt_total[i], h[i]);
}

// ---------------- bucket exclusive scan (single block, 1024 threads) ----------------
__global__ void k_scan_buckets(const int* __restrict__ tot, int* __restrict__ base,
                               int* __restrict__ cur) {
  __shared__ int s[NBKT_MAX];
  int t = threadIdx.x;
  int v = tot[t];
  s[t] = v;
  __syncthreads();
  for (int o = 1; o < NBKT_MAX; o <<= 1) {
    int u = (t >= o) ? s[t - o] : 0;
    __syncthreads();
    s[t] += u;
    __syncthreads();
  }
  int ex = s[t] - v;
  base[t] = ex;
  cur[t]  = ex;
}

// ---------------- pass A: bucket-group records; per-(block,bucket) contiguous segments ----------------
__global__ __launch_bounds__(256) void k_passA(
    const int* __restrict__ dst, const int* __restrict__ rec,
    int* __restrict__ bkt_cursor,
    int* __restrict__ tmp_rec, unsigned short* __restrict__ tmp_dl, int E) {
  __shared__ int h[NBKT_MAX];
  __shared__ int c[NBKT_MAX];
  const int tid = threadIdx.x;
  const int chunk = (E + gridDim.x - 1) / gridDim.x;
  const int c0 = blockIdx.x * chunk;
  const int c1 = (c0 + chunk < E) ? c0 + chunk : E;
  for (int i = tid; i < NBKT_MAX; i += 256) h[i] = 0;
  __syncthreads();
  for (int e = c0 + tid; e < c1; e += 256)
    atomicAdd(&h[dst[e] >> BKT_SH], 1);
  __syncthreads();
  for (int i = tid; i < NBKT_MAX; i += 256)
    c[i] = h[i] ? atomicAdd(&bkt_cursor[i], h[i]) : 0;
  __syncthreads();
  for (int e = c0 + tid; e < c1; e += 256) {
    int d = dst[e];
    int p = atomicAdd(&c[d >> BKT_SH], 1);
    tmp_rec[p] = rec[e];
    tmp_dl[p]  = (unsigned short)(d & (BKT_SZ - 1));
  }
}

// ---------------- pass B: per-bucket counting sort by local dst; emits sd_p, colptr, cnts ----------------
__global__ __launch_bounds__(256) void k_passB(
    const int* __restrict__ tmp_rec, const unsigned short* __restrict__ tmp_dl,
    const int* __restrict__ bkt_base,
    int* __restrict__ sd_p, int* __restrict__ colptr, int* __restrict__ cnts,
    int N, int E, int nbkt) {
  __shared__ int h[BKT_SZ];
  __shared__ int cur[BKT_SZ];
  __shared__ int ps[256];
  const int tid = threadIdx.x;
  const int b = blockIdx.x;
  const int rb = bkt_base[b];
  const int re = (b == nbkt - 1) ? E : bkt_base[b + 1];

  h[tid] = 0; h[tid + 256] = 0;
  __syncthreads();
  for (int r = rb + tid; r < re; r += 256)
    atomicAdd(&h[tmp_dl[r]], 1);
  __syncthreads();

  // exclusive scan over 512 counts: pairwise + Hillis-Steele over 256 partials
  int a0 = h[2*tid], a1 = h[2*tid + 1];
  ps[tid] = a0 + a1;
  __syncthreads();
  for (int o = 1; o < 256; o <<= 1) {
    int u = (tid >= o) ? ps[tid - o] : 0;
    __syncthreads();
    ps[tid] += u;
    __syncthreads();
  }
  int e0 = tid ? ps[tid - 1] : 0;
  int g0 = rb + e0;
  int g1 = g0 + a0;
  cur[2*tid]     = g0;
  cur[2*tid + 1] = g1;
  int node0 = b * BKT_SZ + 2*tid;
  if (node0 < N)     { colptr[node0]     = g0; cnts[node0]     = a0; }
  if (node0 + 1 < N) { colptr[node0 + 1] = g1; cnts[node0 + 1] = a1; }
  if (b == 0 && tid == 0) colptr[N] = E;
  __syncthreads();

  for (int r = rb + tid; r < re; r += 256) {
    int dl = tmp_dl[r];
    int p = atomicAdd(&cur[dl], 1);
    sd_p[p] = tmp_rec[r];
  }
}

// ---------------- edge-attr table: thread per OUTPUT ELEMENT (2M threads) ----------------
__global__ void k_tbl(const float* __restrict__ W1, const float* __restrict__ sub_w,
                      short* __restrict__ tbl, int total) {
  int i = blockIdx.x * 256 + threadIdx.x;     // i over [0, L*2*TBL_BINS*128)
  if (i >= total) return;
  int col  = i & 127;
  int idx  = i >> 7;                           // (l, kind, bin)
  int bin  = idx & (TBL_BINS - 1);
  int kind = (idx >> 11) & 1;
  int l    = idx >> 12;
  float dist = ((float)bin + 0.5f) * (1.0f / TBL_SCALE);
  const float* W1c = W1 + (size_t)l * CAT_DIM * HIDDEN + 128 * HIDDEN;
  float acc = 0.f;
  #pragma unroll
  for (int g = 0; g < 16; ++g) {
    float t = dist - (float)g * (1.0f / 3.0f);
    acc += __expf(-4.5f * t * t) * W1c[g * 128 + col];
  }
  #pragma unroll
  for (int g = 0; g < 16; ++g)
    acc += sub_w[kind * 16 + g] * W1c[(16 + g) * 128 + col];
  tbl[(size_t)idx * 128 + (col & 15) * 8 + (col >> 4)] = f2bf(acc * NEG_L2E);   // idx128, pre-scaled
}

// ---------------- weight packing: B-frag order, K permuted to match storage ----------------
__global__ void k_pack_w1ab(const float* __restrict__ W1, short* __restrict__ Wp, int total) {
  int i = blockIdx.x * blockDim.x + threadIdx.x;
  if (i >= total) return;
  int l = i / L1ABSZ, r = i % L1ABSZ;
  int k = r / 256, n = r % 256;                 // k = original h col (0..63)
  int kp = (k & 15) * 4 + (k >> 4);             // idx64
  int kt = kp >> 5, quad = (kp >> 3) & 3, j = kp & 7;
  int srow = (n < 128) ? k : 64 + k;
  int scol = (n < 128) ? n : n - 128;
  Wp[l * L1ABSZ + ((kt*4 + quad) * 256 + n) * 8 + j] =
      f2bf(W1[(size_t)l * CAT_DIM * HIDDEN + srow * HIDDEN + scol] * NEG_L2E);  // pre-scaled
}
__global__ void k_pack_w2(const float* __restrict__ W, short* __restrict__ Wp, int total) {
  int i = blockIdx.x * blockDim.x + threadIdx.x;
  if (i >= total) return;
  int l = i / L2SZ, r = i % L2SZ;
  int k = r / NODE_DIM, n = r % NODE_DIM;       // k = original hidden col (0..127)
  int kp = (k & 15) * 8 + (k >> 4);             // idx128
  int kt = kp >> 5, quad = (kp >> 3) & 3, j = kp & 7;
  Wp[l * L2SZ + ((kt*4 + quad) * NODE_DIM + n) * 8 + j] = f2bf(W[i]);
}

// ---------------- node kernel: [agg=Sb@W2+cnt*b2; h=relu(h+agg)]  (or: h=embed init)
// ----------------              [pa|pb = h@W1ab -> fp8]            (unless last layer)
// ----------------              [graph mean-pool from ht]          (last layer only)
__global__ __launch_bounds__(256, 4) void k_node(
    short* __restrict__ hb,
    const short* __restrict__ Sb, const int* __restrict__ cnts,
    const int* __restrict__ atoms, const float* __restrict__ embed_w,
    const short* __restrict__ W2p, const float* __restrict__ b2,
    const short* __restrict__ W1abp, const float* __restrict__ b1,
    unsigned char* __restrict__ pa, unsigned char* __restrict__ pb,
    const int* __restrict__ batch_ids, float* __restrict__ pooled,
    float* __restrict__ cntg, int N)
{
  __shared__ short ht[64 * 72];

  const int tid  = threadIdx.x;
  const int lane = tid & 63;
  const int w    = tid >> 6;
  const int quad = lane >> 4;
  const int l16  = lane & 15;
  const int base = blockIdx.x * 64 + w * 16;

  if (W2p) {
    float4v acc[4];
    #pragma unroll
    for (int nt = 0; nt < 4; ++nt) acc[nt] = (float4v)0.f;
    const int arow = base + l16;
    const bool av = arow < N;
    #pragma unroll
    for (int kt = 0; kt < 4; ++kt) {
      short8 a = av ? *(const short8*)&Sb[(size_t)arow * 128 + kt*32 + quad*8]
                    : (short8)0;
      #pragma unroll
      for (int nt = 0; nt < 4; ++nt) {
        short8 b = *(const short8*)&W2p[((kt*4 + quad) * NODE_DIM + nt*16 + l16) * 8];
        acc[nt] = __builtin_amdgcn_mfma_f32_16x16x32_bf16(a, b, acc[nt], 0, 0, 0);
      }
    }
    float bb[4];
    #pragma unroll
    for (int nt = 0; nt < 4; ++nt) bb[nt] = b2[nt*16 + l16];
    #pragma unroll
    for (int r = 0; r < 4; ++r) {
      int row  = base + quad*4 + r;
      int lrow = w*16 + quad*4 + r;
      if (row < N) {
        float cf = (float)cnts[row];
        short4v hv = *(const short4v*)&hb[(size_t)row * 64 + l16*4];  // permuted pos l16*4+nt
        float v0 = fmaxf(bf2f(hv[0]) + acc[0][r] + cf * bb[0], 0.f);
        float v1 = fmaxf(bf2f(hv[1]) + acc[1][r] + cf * bb[1], 0.f);
        float v2 = fmaxf(bf2f(hv[2]) + acc[2][r] + cf * bb[2], 0.f);
        float v3 = fmaxf(bf2f(hv[3]) + acc[3][r] + cf * bb[3], 0.f);
        short4v hs = {f2bf(v0), f2bf(v1), f2bf(v2), f2bf(v3)};
        if (!pooled) *(short4v*)&hb[(size_t)row * 64 + l16*4] = hs;  // dead after pool
        *(short4v*)&ht[lrow * 72 + l16*4] = hs;
      } else {
        *(short4v*)&ht[lrow * 72 + l16*4] = (short4v)0;
      }
    }
  } else {
    // first layer: h = embed_w[atoms] (idx64-permuted), staged to ht and hb
    int row = base + l16;
    const bool rv = row < N;
    int aid = rv ? atoms[row] : 0;
    #pragma unroll
    for (int c = 0; c < 2; ++c) {
      int colc = quad*16 + c*8;
      short8 v;
      #pragma unroll
      for (int k = 0; k < 8; ++k) {
        int p = colc + k;
        int col = (p & 3) * 16 + (p >> 2);      // inverse idx64
        v[k] = rv ? f2bf(embed_w[aid * NODE_DIM + col]) : (short)0;
      }
      *(short8*)&ht[(w*16 + l16) * 72 + colc] = v;
      if (rv) *(short8*)&hb[(size_t)row * 64 + colc] = v;
    }
  }

  if (W1abp) {
    float4v acc[16];
    #pragma unroll
    for (int nt = 0; nt < 16; ++nt) acc[nt] = (float4v)0.f;
    #pragma unroll
    for (int kt = 0; kt < 2; ++kt) {
      short8 a = *(const short8*)&ht[(w*16 + l16) * 72 + kt*32 + quad*8];
      #pragma unroll
      for (int nt = 0; nt < 16; ++nt) {
        short8 b = *(const short8*)&W1abp[((kt*4 + quad) * 256 + nt*16 + l16) * 8];
        acc[nt] = __builtin_amdgcn_mfma_f32_16x16x32_bf16(a, b, acc[nt], 0, 0, 0);
      }
    }
    float b1a[8];
    #pragma unroll
    for (int nt = 0; nt < 8; ++nt) b1a[nt] = b1[nt*16 + l16] * NEG_L2E;  // pre-scaled bias
    #pragma unroll
    for (int r = 0; r < 4; ++r) {
      int row = base + quad*4 + r;
      if (row < N) {
        // pa half -> fp8 e4m3 (HW pack, RNE): byte k = permuted col l16*8+k
        int a0 = 0, a1 = 0;
        a0 = __builtin_amdgcn_cvt_pk_fp8_f32(acc[0][r] + b1a[0], acc[1][r] + b1a[1], a0, false);
        a0 = __builtin_amdgcn_cvt_pk_fp8_f32(acc[2][r] + b1a[2], acc[3][r] + b1a[3], a0, true);
        a1 = __builtin_amdgcn_cvt_pk_fp8_f32(acc[4][r] + b1a[4], acc[5][r] + b1a[5], a1, false);
        a1 = __builtin_amdgcn_cvt_pk_fp8_f32(acc[6][r] + b1a[6], acc[7][r] + b1a[7], a1, true);
        uint2 pka; pka.x = (unsigned)a0; pka.y = (unsigned)a1;
        *(uint2*)&pa[(size_t)row * 128 + l16*8] = pka;
        // pb half -> fp8 e4m3
        int w0 = 0, w1 = 0;
        w0 = __builtin_amdgcn_cvt_pk_fp8_f32(acc[8][r],  acc[9][r],  w0, false);
        w0 = __builtin_amdgcn_cvt_pk_fp8_f32(acc[10][r], acc[11][r], w0, true);
        w1 = __builtin_amdgcn_cvt_pk_fp8_f32(acc[12][r], acc[13][r], w1, false);
        w1 = __builtin_amdgcn_cvt_pk_fp8_f32(acc[14][r], acc[15][r], w1, true);
        uint2 pk8; pk8.x = (unsigned)w0; pk8.y = (unsigned)w1;
        *(uint2*)&pb[(size_t)row * 128 + l16*8] = pk8;
      }
    }
  }

  if (pooled) {
    // graph mean-pool: wave pools its own 16 ht rows (written by this wave above);
    // batch_ids sorted -> short segment runs; lane = permuted col
    float acc = 0.f;
    int   cnt = 0;
    int  gcur = -1;
    for (int i = 0; i < 16; ++i) {
      int node = base + i;
      if (node >= N) break;
      int g = batch_ids[node];
      if (g != gcur) {
        if (gcur >= 0) {
          atomicAdd(&pooled[gcur * NODE_DIM + lane], acc);
          if (lane == 0) atomicAdd(&cntg[gcur], (float)cnt);
        }
        gcur = g; acc = 0.f; cnt = 0;
      }
      acc += bf2f(ht[(w*16 + i) * 72 + lane]);
      cnt++;
    }
    if (gcur >= 0) {
      atomicAdd(&pooled[gcur * NODE_DIM + lane], acc);
      if (lane == 0) atomicAdd(&cntg[gcur], (float)cnt);
    }
  }
}

// ---------------- gather kernel: wave per node, scalar record stream, fp8 pa/pb rows ----------------
__global__ __launch_bounds__(256, 8) void k_gather(
    const unsigned char* __restrict__ pa, const unsigned char* __restrict__ pb,
    const short* __restrict__ tblL,
    const int* __restrict__ sd_p, const int* __restrict__ colptr,
    short* __restrict__ Sb, int N)
{
  int n = blockIdx.x * 4 + (threadIdx.x >> 6);
  if (n >= N) return;
  const int lane = threadIdx.x & 63;
  const int d2 = lane * 2;                 // byte offset in 128 B fp8 row / short idx in Sb
  const int d4 = lane * 4;                 // byte offset within a 256 B bf16 row

  // wave-uniform edge range -> scalar (SALU) bounds, uniform branches
  const int s = __builtin_amdgcn_readfirstlane(colptr[n]);
  const int e = __builtin_amdgcn_readfirstlane(colptr[n + 1]);

  unsigned short upa = *(const unsigned short*)&pa[(size_t)n * 128 + d2];
  floatx2 pv = __builtin_amdgcn_cvt_pk_f32_fp8((int)upa, false);
  const float p0 = pv[0], p1 = pv[1];      // pre-scaled: p = -log2e * (h@W1a + b1)
  float s0 = 0.f, s1 = 0.f;

  const char* pbB = (const char*)pb;
  const char* tbB = (const char*)tblL;

  if (e > s) {
    unsigned short ub0[4], ub1[4];
    unsigned ue0[4], ue1[4];

    auto load4 = [&](unsigned short (&ub)[4], unsigned (&ue)[4], int j) {
      #pragma unroll
      for (int t = 0; t < 4; ++t) {
        int jj = (j + t < e) ? j + t : s;       // scalar clamp: always a valid record
        int rc = __builtin_amdgcn_readfirstlane(sd_p[jj]);  // wave-uniform record
        // scalar row bases + per-lane offset -> global_load v, v_off, s[base]
        const char* pr = pbB + ((size_t)((unsigned)rc >> 12) << 7);   // 128 B fp8 rows
        const char* tr = tbB + ((size_t)(rc & 0xfff) << 8);           // 256 B bf16 rows
        ub[t] = *(const unsigned short*)(pr + d2);
        ue[t] = *(const unsigned*)(tr + d4);
      }
    };
    // y = -x*log2e (all inputs pre-scaled); exp2(y)=e^-x; acc += y/(1+e^-x);
    // final un-scale by -ln2 recovers sum of x*sigmoid(x).
    auto consume4 = [&](unsigned short (&ub)[4], unsigned (&ue)[4], int j) {
      #pragma unroll
      for (int t = 0; t < 4; ++t) {
        if (j + t < e) {                        // wave-uniform branch
          floatx2 bv = __builtin_amdgcn_cvt_pk_f32_fp8((int)ub[t], false);  // 2 fp8 -> 2 f32
          float y0 = p0 + bv[0] + bflo(ue[t]);
          float y1 = p1 + bv[1] + bfhi(ue[t]);
          s0 += y0 * __builtin_amdgcn_rcpf(1.f + hw_exp2(y0));
          s1 += y1 * __builtin_amdgcn_rcpf(1.f + hw_exp2(y1));
        }
      }
    };

    load4(ub0, ue0, s);
    int j = s;
    for (; j + 4 < e; j += 8) {
      load4(ub1, ue1, j + 4);
      consume4(ub0, ue0, j);
      if (j + 8 < e) load4(ub0, ue0, j + 8);
      consume4(ub1, ue1, j + 4);
    }
    if (j < e) consume4(ub0, ue0, j);
  }

  s0 *= NEG_LN2;
  s1 *= NEG_LN2;
  unsigned pk = ((unsigned)(unsigned short)f2bf(s1) << 16) | (unsigned short)f2bf(s0);
  *(unsigned*)&Sb[(size_t)n * 128 + d2] = pk;
}

// final linear: un-permute fc_w (pooled is idx64-permuted)
__global__ void k_final(const float* __restrict__ pooled, const float* __restrict__ counts,
                        const float* __restrict__ fc_w, const float* __restrict__ fc_b,
                        float* __restrict__ out, int G) {
  int g = blockIdx.x * blockDim.x + threadIdx.x;
  if (g < G) {
    float acc = 0.f;
    for (int d = 0; d < NODE_DIM; ++d) {
      int col = (d & 3) * 16 + (d >> 2);      // inverse idx64
      acc += pooled[g * NODE_DIM + d] * fc_w[col];
    }
    float c = counts[g];
    if (c < 1.f) c = 1.f;
    out[g] = acc / c + fc_b[0];
  }
}

extern "C" void kernel_launch(void* const* d_in, const int* in_sizes, int n_in,
                              void* d_out, int out_size, void* d_ws, size_t ws_size,
                              hipStream_t stream) {
  const int*   atoms   = (const int*)  d_in[0];
  const int*   eidx    = (const int*)  d_in[1];
  const float* coords  = (const float*)d_in[2];
  const int*   isr     = (const int*)  d_in[3];
  const int*   batch   = (const int*)  d_in[4];
  const float* embed_w = (const float*)d_in[5];
  const float* sub_w   = (const float*)d_in[6];
  const float* W1      = (const float*)d_in[7];
  const float* b1      = (const float*)d_in[8];
  const float* W2      = (const float*)d_in[9];
  const float* b2      = (const float*)d_in[10];
  const float* fc_w    = (const float*)d_in[11];
  const float* fc_b    = (const float*)d_in[12];
  float* out = (float*)d_out;

  const int N = in_sizes[0];
  const int E = in_sizes[1] / 2;
  const int L = in_sizes[8] / HIDDEN;
  const int G = out_size;

  const int* srcv = eidx;
  const int* dstv = eidx + E;

  size_t off = 0;
  auto carve = [&](size_t bytes) -> char* {
    char* p = (char*)d_ws + off;
    off += (bytes + 255) & ~(size_t)255;
    return p;
  };
  short* hb       = (short*)carve((size_t)N * NODE_DIM * 2);
  short* Sb       = (short*)carve((size_t)N * HIDDEN * 2);
  unsigned char* pa = (unsigned char*)carve((size_t)N * HIDDEN);   // fp8 e4m3
  unsigned char* pb = (unsigned char*)carve((size_t)N * HIDDEN);   // fp8 e4m3
  int*   rec      = (int*)  carve((size_t)E * 4);
  int*   sd_p     = (int*)  carve((size_t)E * 4);
  int*   tmp_rec  = (int*)  carve((size_t)E * 4);
  unsigned short* tmp_dl = (unsigned short*)carve((size_t)E * 2);
  int*   cnts     = (int*)  carve((size_t)N * 4);
  int*   colptr   = (int*)  carve(((size_t)N + 2) * 4);
  int*   bkt_total  = (int*)carve((size_t)NBKT_MAX * 4);
  int*   bkt_base   = (int*)carve((size_t)(NBKT_MAX + 1) * 4);
  int*   bkt_cursor = (int*)carve((size_t)NBKT_MAX * 4);
  short* W1abp    = (short*)carve((size_t)L * L1ABSZ * 2);
  short* W2p      = (short*)carve((size_t)L * L2SZ * 2);
  short* tbl      = (short*)carve((size_t)L * TBLSZ * 2);
  float* pooled   = (float*)carve((size_t)G * NODE_DIM * 4);
  float* cntg     = (float*)carve((size_t)G * 4);

  const int nbkt = (N + BKT_SZ - 1) / BKT_SZ;

  k_zero_i<<<(NBKT_MAX + 255) / 256, 256, 0, stream>>>(bkt_total, NBKT_MAX);
  k_edge_pre<<<512, 256, 0, stream>>>(srcv, dstv, coords, isr, rec, bkt_total, E);
  k_zero_f<<<(G * NODE_DIM + G + 255) / 256, 256, 0, stream>>>(pooled, G * NODE_DIM + G);
  k_scan_buckets<<<1, NBKT_MAX, 0, stream>>>(bkt_total, bkt_base, bkt_cursor);
  k_passA<<<256, 256, 0, stream>>>(dstv, rec, bkt_cursor, tmp_rec, tmp_dl, E);
  k_passB<<<nbkt, 256, 0, stream>>>(tmp_rec, tmp_dl, bkt_base, sd_p, colptr, cnts, N, E, nbkt);
  k_pack_w1ab<<<(L * L1ABSZ + 255) / 256, 256, 0, stream>>>(W1, W1abp, L * L1ABSZ);
  k_pack_w2<<<(L * L2SZ + 255) / 256, 256, 0, stream>>>(W2, W2p, L * L2SZ);
  k_tbl<<<(L * 2 * TBL_BINS * 128 + 255) / 256, 256, 0, stream>>>(W1, sub_w, tbl,
                                                                  L * 2 * TBL_BINS * 128);

  const int nblk_n = (N + 63) / 64;
  const int nblk_g = (N + 3) / 4;

  // first projection (embed init fused): pa|pb = embed(h) @ W1ab[0]
  k_node<<<nblk_n, 256, 0, stream>>>(
      hb, (const short*)nullptr, (const int*)nullptr,
      atoms, embed_w,
      (const short*)nullptr, (const float*)nullptr,
      W1abp, b1, pa, pb,
      (const int*)nullptr, (float*)nullptr, (float*)nullptr, N);

  for (int l = 0; l < L; ++l) {
    const bool last = (l == L - 1);
    k_gather<<<nblk_g, 256, 0, stream>>>(pa, pb, tbl + (size_t)l * TBLSZ,
                                         sd_p, colptr, Sb, N);
    k_node<<<nblk_n, 256, 0, stream>>>(
        hb, Sb, cnts,
        (const int*)nullptr, (const float*)nullptr,
        W2p + (size_t)l * L2SZ, b2 + (size_t)l * NODE_DIM,
        last ? (const short*)nullptr : W1abp + (size_t)(l + 1) * L1ABSZ,
        last ? (const float*)nullptr : b1 + (size_t)(l + 1) * HIDDEN,
        pa, pb,
        last ? batch : (const int*)nullptr,
        last ? pooled : (float*)nullptr,
        last ? cntg : (float*)nullptr, N);
  }

  k_final<<<1, 64, 0, stream>>>(pooled, cntg, fc_w, fc_b, out, G);
}

// Round 12
// 515.408 us; speedup vs baseline: 1.0529x; 1.0529x over previous
//
#include <hip/hip_runtime.h>
#include <hip/hip_bf16.h>
#include <math.h>

#define NODE_DIM  64
#define EDGE_DIM  32
#define NUM_GAUSS 16
#define HIDDEN    128
#define CAT_DIM   160
#define TBL_BINS  2048
#define TBL_SCALE 256.0f                // bins per unit distance (domain [0,8))
#define L1ABSZ    (64 * 256)            // packed W1ab per layer (K=64, N=256)
#define L2SZ      (HIDDEN * NODE_DIM)   // packed W2 per layer   (K=128, N=64)
#define TBLSZ     (2 * TBL_BINS * 128)  // per-layer edge-attr table entries

// Pre-scale: pa/pb/tbl carry value * -log2(e); gather uses exp2 directly and
// un-scales the accumulated sum by -ln(2) once per node.
#define NEG_L2E   (-1.442695040888963f)
#define NEG_LN2   (-0.6931471805599453f)

// CSR build buckets: 512 nodes per bucket, max 1024 buckets (N <= 524288)
#define BKT_SH    9
#define BKT_SZ    512
#define NBKT_MAX  1024

// Column-permuted storage: idx64(c)=(c&15)*4+(c>>4)  (64-wide: hb, ht)
//                          idx128(c)=(c&15)*8+(c>>4) (128-wide: pa, pb, tbl, Sb)
// Weights' K dims are packed with the same permutation, so all GEMMs are invariant.
// Edge record: rec = (src << 12) | ety   (src<2^20, ety<2^12) — single 4 B scatter.
// h is carried in bf16 only (hb).
// pa AND pb (the gathered message halves) are stored FP8 e4m3 (128 B rows) to halve
// the gather-path traffic; tbl and Sb stay bf16.

typedef __attribute__((ext_vector_type(8))) short short8;
typedef __attribute__((ext_vector_type(4))) short short4v;
typedef __attribute__((ext_vector_type(4))) float float4v;
typedef __attribute__((ext_vector_type(2))) float floatx2;

static __device__ __forceinline__ short f2bf(float x) {
  __hip_bfloat16 h = __float2bfloat16(x);
  return *reinterpret_cast<short*>(&h);
}
static __device__ __forceinline__ float bf2f(short s) {
  return __uint_as_float(((unsigned)(unsigned short)s) << 16);
}
static __device__ __forceinline__ float bflo(unsigned u) { return __uint_as_float(u << 16); }
static __device__ __forceinline__ float bfhi(unsigned u) { return __uint_as_float(u & 0xffff0000u); }

#if defined(__has_builtin) && __has_builtin(__builtin_amdgcn_exp2f)
static __device__ __forceinline__ float hw_exp2(float x) { return __builtin_amdgcn_exp2f(x); }
#else
static __device__ __forceinline__ float hw_exp2(float x) { return exp2f(x); }
#endif

// ---------------- init: hb (idx64-permuted) = embed[atoms] ----------------
__global__ void k_init(const int* __restrict__ atoms, const float* __restrict__ embed_w,
                       short* __restrict__ hb, int n) {
  int stride = gridDim.x * blockDim.x;
  for (int i = blockIdx.x * blockDim.x + threadIdx.x; i < n; i += stride) {
    int p = i & 63;
    int col = (p & 3) * 16 + (p >> 2);          // inverse idx64
    hb[i] = f2bf(embed_w[atoms[i >> 6] * NODE_DIM + col]);
  }
}

__global__ void k_zero_f(float* __restrict__ p, int n) {
  int stride = gridDim.x * blockDim.x;
  for (int i = blockIdx.x * blockDim.x + threadIdx.x; i < n; i += stride) p[i] = 0.f;
}
__global__ void k_zero_i(int* __restrict__ p, int n) {
  int i = blockIdx.x * blockDim.x + threadIdx.x;
  if (i < n) p[i] = 0;
}

// ---------------- edge precompute: rec = (src<<12)|(kind<<11)|bin; LDS bucket histogram ----------------
__global__ __launch_bounds__(256) void k_edge_pre(
    const int* __restrict__ src, const int* __restrict__ dst,
    const float* __restrict__ coords, const int* __restrict__ isr,
    int* __restrict__ rec, int* __restrict__ bkt_total, int E) {
  __shared__ int h[NBKT_MAX];
  for (int i = threadIdx.x; i < NBKT_MAX; i += 256) h[i] = 0;
  __syncthreads();
  int stride = gridDim.x * blockDim.x;
  for (int e = blockIdx.x * blockDim.x + threadIdx.x; e < E; e += stride) {
    int s = src[e], d = dst[e];
    float dx = coords[s*3+0] - coords[d*3+0];
    float dy = coords[s*3+1] - coords[d*3+1];
    float dz = coords[s*3+2] - coords[d*3+2];
    float dist = sqrtf(dx*dx + dy*dy + dz*dz);
    int bin = (int)(dist * TBL_SCALE);
    bin = (bin > TBL_BINS - 1) ? TBL_BINS - 1 : bin;
    int kind = (isr[s] != isr[d]) ? 1 : 0;
    rec[e] = (s << 12) | (kind << 11) | bin;
    atomicAdd(&h[d >> BKT_SH], 1);
  }
  __syncthreads();
  for (int i = threadIdx.x; i < NBKT_MAX; i += 256)
    if (h[i]) atomicAdd(&bkt_total[i], h[i]);
}

// ---------------- bucket exclusive scan (single block, 1024 threads) ----------------
__global__ void k_scan_buckets(const int* __restrict__ tot, int* __restrict__ base,
                               int* __restrict__ cur) {
  __shared__ int s[NBKT_MAX];
  int t = threadIdx.x;
  int v = tot[t];
  s[t] = v;
  __syncthreads();
  for (int o = 1; o < NBKT_MAX; o <<= 1) {
    int u = (t >= o) ? s[t - o] : 0;
    __syncthreads();
    s[t] += u;
    __syncthreads();
  }
  int ex = s[t] - v;
  base[t] = ex;
  cur[t]  = ex;
}

// ---------------- pass A: bucket-group records; per-(block,bucket) contiguous segments ----------------
__global__ __launch_bounds__(256) void k_passA(
    const int* __restrict__ dst, const int* __restrict__ rec,
    int* __restrict__ bkt_cursor,
    int* __restrict__ tmp_rec, unsigned short* __restrict__ tmp_dl, int E) {
  __shared__ int h[NBKT_MAX];
  __shared__ int c[NBKT_MAX];
  const int tid = threadIdx.x;
  const int chunk = (E + gridDim.x - 1) / gridDim.x;
  const int c0 = blockIdx.x * chunk;
  const int c1 = (c0 + chunk < E) ? c0 + chunk : E;
  for (int i = tid; i < NBKT_MAX; i += 256) h[i] = 0;
  __syncthreads();
  for (int e = c0 + tid; e < c1; e += 256)
    atomicAdd(&h[dst[e] >> BKT_SH], 1);
  __syncthreads();
  for (int i = tid; i < NBKT_MAX; i += 256)
    c[i] = h[i] ? atomicAdd(&bkt_cursor[i], h[i]) : 0;
  __syncthreads();
  for (int e = c0 + tid; e < c1; e += 256) {
    int d = dst[e];
    int p = atomicAdd(&c[d >> BKT_SH], 1);
    tmp_rec[p] = rec[e];
    tmp_dl[p]  = (unsigned short)(d & (BKT_SZ - 1));
  }
}

// ---------------- pass B: per-bucket counting sort by local dst; emits sd_p, colptr, cnts ----------------
__global__ __launch_bounds__(256) void k_passB(
    const int* __restrict__ tmp_rec, const unsigned short* __restrict__ tmp_dl,
    const int* __restrict__ bkt_base,
    int* __restrict__ sd_p, int* __restrict__ colptr, int* __restrict__ cnts,
    int N, int E, int nbkt) {
  __shared__ int h[BKT_SZ];
  __shared__ int cur[BKT_SZ];
  __shared__ int ps[256];
  const int tid = threadIdx.x;
  const int b = blockIdx.x;
  const int rb = bkt_base[b];
  const int re = (b == nbkt - 1) ? E : bkt_base[b + 1];

  h[tid] = 0; h[tid + 256] = 0;
  __syncthreads();
  for (int r = rb + tid; r < re; r += 256)
    atomicAdd(&h[tmp_dl[r]], 1);
  __syncthreads();

  // exclusive scan over 512 counts: pairwise + Hillis-Steele over 256 partials
  int a0 = h[2*tid], a1 = h[2*tid + 1];
  ps[tid] = a0 + a1;
  __syncthreads();
  for (int o = 1; o < 256; o <<= 1) {
    int u = (tid >= o) ? ps[tid - o] : 0;
    __syncthreads();
    ps[tid] += u;
    __syncthreads();
  }
  int e0 = tid ? ps[tid - 1] : 0;
  int g0 = rb + e0;
  int g1 = g0 + a0;
  cur[2*tid]     = g0;
  cur[2*tid + 1] = g1;
  int node0 = b * BKT_SZ + 2*tid;
  if (node0 < N)     { colptr[node0]     = g0; cnts[node0]     = a0; }
  if (node0 + 1 < N) { colptr[node0 + 1] = g1; cnts[node0 + 1] = a1; }
  if (b == 0 && tid == 0) colptr[N] = E;
  __syncthreads();

  for (int r = rb + tid; r < re; r += 256) {
    int dl = tmp_dl[r];
    int p = atomicAdd(&cur[dl], 1);
    sd_p[p] = tmp_rec[r];
  }
}

// ---------------- edge-attr table: thread per OUTPUT ELEMENT (2M threads) ----------------
__global__ void k_tbl(const float* __restrict__ W1, const float* __restrict__ sub_w,
                      short* __restrict__ tbl, int total) {
  int i = blockIdx.x * 256 + threadIdx.x;     // i over [0, L*2*TBL_BINS*128)
  if (i >= total) return;
  int col  = i & 127;
  int idx  = i >> 7;                           // (l, kind, bin)
  int bin  = idx & (TBL_BINS - 1);
  int kind = (idx >> 11) & 1;
  int l    = idx >> 12;
  float dist = ((float)bin + 0.5f) * (1.0f / TBL_SCALE);
  const float* W1c = W1 + (size_t)l * CAT_DIM * HIDDEN + 128 * HIDDEN;
  float acc = 0.f;
  #pragma unroll
  for (int g = 0; g < 16; ++g) {
    float t = dist - (float)g * (1.0f / 3.0f);
    acc += __expf(-4.5f * t * t) * W1c[g * 128 + col];
  }
  #pragma unroll
  for (int g = 0; g < 16; ++g)
    acc += sub_w[kind * 16 + g] * W1c[(16 + g) * 128 + col];
  tbl[(size_t)idx * 128 + (col & 15) * 8 + (col >> 4)] = f2bf(acc * NEG_L2E);   // idx128, pre-scaled
}

// ---------------- weight packing: B-frag order, K permuted to match storage ----------------
__global__ void k_pack_w1ab(const float* __restrict__ W1, short* __restrict__ Wp, int total) {
  int i = blockIdx.x * blockDim.x + threadIdx.x;
  if (i >= total) return;
  int l = i / L1ABSZ, r = i % L1ABSZ;
  int k = r / 256, n = r % 256;                 // k = original h col (0..63)
  int kp = (k & 15) * 4 + (k >> 4);             // idx64
  int kt = kp >> 5, quad = (kp >> 3) & 3, j = kp & 7;
  int srow = (n < 128) ? k : 64 + k;
  int scol = (n < 128) ? n : n - 128;
  Wp[l * L1ABSZ + ((kt*4 + quad) * 256 + n) * 8 + j] =
      f2bf(W1[(size_t)l * CAT_DIM * HIDDEN + srow * HIDDEN + scol] * NEG_L2E);  // pre-scaled
}
__global__ void k_pack_w2(const float* __restrict__ W, short* __restrict__ Wp, int total) {
  int i = blockIdx.x * blockDim.x + threadIdx.x;
  if (i >= total) return;
  int l = i / L2SZ, r = i % L2SZ;
  int k = r / NODE_DIM, n = r % NODE_DIM;       // k = original hidden col (0..127)
  int kp = (k & 15) * 8 + (k >> 4);             // idx128
  int kt = kp >> 5, quad = (kp >> 3) & 3, j = kp & 7;
  Wp[l * L2SZ + ((kt*4 + quad) * NODE_DIM + n) * 8 + j] = f2bf(W[i]);
}

// ---------------- node kernel: [agg=Sb@W2+cnt*b2; h=relu(h+agg)] ; [pa|pb = h@W1ab -> fp8] ----------------
__global__ __launch_bounds__(256, 4) void k_node(
    short* __restrict__ hb,
    const short* __restrict__ Sb, const int* __restrict__ cnts,
    const short* __restrict__ W2p, const float* __restrict__ b2,
    const short* __restrict__ W1abp, const float* __restrict__ b1,
    unsigned char* __restrict__ pa, unsigned char* __restrict__ pb, int N)
{
  __shared__ short ht[64 * 72];

  const int tid  = threadIdx.x;
  const int lane = tid & 63;
  const int w    = tid >> 6;
  const int quad = lane >> 4;
  const int l16  = lane & 15;
  const int base = blockIdx.x * 64 + w * 16;

  if (W2p) {
    float4v acc[4];
    #pragma unroll
    for (int nt = 0; nt < 4; ++nt) acc[nt] = (float4v)0.f;
    const int arow = base + l16;
    const bool av = arow < N;
    #pragma unroll
    for (int kt = 0; kt < 4; ++kt) {
      short8 a = av ? *(const short8*)&Sb[(size_t)arow * 128 + kt*32 + quad*8]
                    : (short8)0;
      #pragma unroll
      for (int nt = 0; nt < 4; ++nt) {
        short8 b = *(const short8*)&W2p[((kt*4 + quad) * NODE_DIM + nt*16 + l16) * 8];
        acc[nt] = __builtin_amdgcn_mfma_f32_16x16x32_bf16(a, b, acc[nt], 0, 0, 0);
      }
    }
    float bb[4];
    #pragma unroll
    for (int nt = 0; nt < 4; ++nt) bb[nt] = b2[nt*16 + l16];
    #pragma unroll
    for (int r = 0; r < 4; ++r) {
      int row  = base + quad*4 + r;
      int lrow = w*16 + quad*4 + r;
      if (row < N) {
        float cf = (float)cnts[row];
        short4v hv = *(const short4v*)&hb[(size_t)row * 64 + l16*4];  // permuted pos l16*4+nt
        float v0 = fmaxf(bf2f(hv[0]) + acc[0][r] + cf * bb[0], 0.f);
        float v1 = fmaxf(bf2f(hv[1]) + acc[1][r] + cf * bb[1], 0.f);
        float v2 = fmaxf(bf2f(hv[2]) + acc[2][r] + cf * bb[2], 0.f);
        float v3 = fmaxf(bf2f(hv[3]) + acc[3][r] + cf * bb[3], 0.f);
        short4v hs = {f2bf(v0), f2bf(v1), f2bf(v2), f2bf(v3)};
        *(short4v*)&hb[(size_t)row * 64 + l16*4] = hs;
        *(short4v*)&ht[lrow * 72 + l16*4] = hs;
      } else {
        *(short4v*)&ht[lrow * 72 + l16*4] = (short4v)0;
      }
    }
  } else {
    int row = base + l16;
    #pragma unroll
    for (int c = 0; c < 2; ++c) {
      int colc = quad*16 + c*8;
      short8 v = (row < N) ? *(const short8*)&hb[(size_t)row * 64 + colc] : (short8)0;
      *(short8*)&ht[(w*16 + l16) * 72 + colc] = v;
    }
  }

  if (W1abp) {
    float4v acc[16];
    #pragma unroll
    for (int nt = 0; nt < 16; ++nt) acc[nt] = (float4v)0.f;
    #pragma unroll
    for (int kt = 0; kt < 2; ++kt) {
      short8 a = *(const short8*)&ht[(w*16 + l16) * 72 + kt*32 + quad*8];
      #pragma unroll
      for (int nt = 0; nt < 16; ++nt) {
        short8 b = *(const short8*)&W1abp[((kt*4 + quad) * 256 + nt*16 + l16) * 8];
        acc[nt] = __builtin_amdgcn_mfma_f32_16x16x32_bf16(a, b, acc[nt], 0, 0, 0);
      }
    }
    float b1a[8];
    #pragma unroll
    for (int nt = 0; nt < 8; ++nt) b1a[nt] = b1[nt*16 + l16] * NEG_L2E;  // pre-scaled bias
    #pragma unroll
    for (int r = 0; r < 4; ++r) {
      int row = base + quad*4 + r;
      if (row < N) {
        // pa half -> fp8 e4m3 (HW pack, RNE): byte k = permuted col l16*8+k
        int a0 = 0, a1 = 0;
        a0 = __builtin_amdgcn_cvt_pk_fp8_f32(acc[0][r] + b1a[0], acc[1][r] + b1a[1], a0, false);
        a0 = __builtin_amdgcn_cvt_pk_fp8_f32(acc[2][r] + b1a[2], acc[3][r] + b1a[3], a0, true);
        a1 = __builtin_amdgcn_cvt_pk_fp8_f32(acc[4][r] + b1a[4], acc[5][r] + b1a[5], a1, false);
        a1 = __builtin_amdgcn_cvt_pk_fp8_f32(acc[6][r] + b1a[6], acc[7][r] + b1a[7], a1, true);
        uint2 pka; pka.x = (unsigned)a0; pka.y = (unsigned)a1;
        *(uint2*)&pa[(size_t)row * 128 + l16*8] = pka;
        // pb half -> fp8 e4m3
        int w0 = 0, w1 = 0;
        w0 = __builtin_amdgcn_cvt_pk_fp8_f32(acc[8][r],  acc[9][r],  w0, false);
        w0 = __builtin_amdgcn_cvt_pk_fp8_f32(acc[10][r], acc[11][r], w0, true);
        w1 = __builtin_amdgcn_cvt_pk_fp8_f32(acc[12][r], acc[13][r], w1, false);
        w1 = __builtin_amdgcn_cvt_pk_fp8_f32(acc[14][r], acc[15][r], w1, true);
        uint2 pk8; pk8.x = (unsigned)w0; pk8.y = (unsigned)w1;
        *(uint2*)&pb[(size_t)row * 128 + l16*8] = pk8;
      }
    }
  }
}

// ---------------- gather kernel: wave per node, scalar record stream, fp8 pa/pb rows ----------------
__global__ __launch_bounds__(256, 8) void k_gather(
    const unsigned char* __restrict__ pa, const unsigned char* __restrict__ pb,
    const short* __restrict__ tblL,
    const int* __restrict__ sd_p, const int* __restrict__ colptr,
    short* __restrict__ Sb, int N)
{
  int n = blockIdx.x * 4 + (threadIdx.x >> 6);
  if (n >= N) return;
  const int lane = threadIdx.x & 63;
  const int d2 = lane * 2;                 // byte offset in 128 B fp8 row / short idx in Sb
  const int d4 = lane * 4;                 // byte offset within a 256 B bf16 row

  // wave-uniform edge range -> scalar (SALU) bounds, uniform branches
  const int s = __builtin_amdgcn_readfirstlane(colptr[n]);
  const int e = __builtin_amdgcn_readfirstlane(colptr[n + 1]);

  unsigned short upa = *(const unsigned short*)&pa[(size_t)n * 128 + d2];
  floatx2 pv = __builtin_amdgcn_cvt_pk_f32_fp8((int)upa, false);
  const float p0 = pv[0], p1 = pv[1];      // pre-scaled: p = -log2e * (h@W1a + b1)
  float s0 = 0.f, s1 = 0.f;

  const char* pbB = (const char*)pb;
  const char* tbB = (const char*)tblL;

  if (e > s) {
    unsigned short ub0[4], ub1[4];
    unsigned ue0[4], ue1[4];

    auto load4 = [&](unsigned short (&ub)[4], unsigned (&ue)[4], int j) {
      #pragma unroll
      for (int t = 0; t < 4; ++t) {
        int jj = (j + t < e) ? j + t : s;       // scalar clamp: always a valid record
        int rc = __builtin_amdgcn_readfirstlane(sd_p[jj]);  // wave-uniform record
        // scalar row bases + per-lane offset -> global_load v, v_off, s[base]
        const char* pr = pbB + ((size_t)((unsigned)rc >> 12) << 7);   // 128 B fp8 rows
        const char* tr = tbB + ((size_t)(rc & 0xfff) << 8);           // 256 B bf16 rows
        ub[t] = *(const unsigned short*)(pr + d2);
        ue[t] = *(const unsigned*)(tr + d4);
      }
    };
    // y = -x*log2e (all inputs pre-scaled); exp2(y)=e^-x; acc += y/(1+e^-x);
    // final un-scale by -ln2 recovers sum of x*sigmoid(x).
    auto consume4 = [&](unsigned short (&ub)[4], unsigned (&ue)[4], int j) {
      #pragma unroll
      for (int t = 0; t < 4; ++t) {
        if (j + t < e) {                        // wave-uniform branch
          floatx2 bv = __builtin_amdgcn_cvt_pk_f32_fp8((int)ub[t], false);  // 2 fp8 -> 2 f32
          float y0 = p0 + bv[0] + bflo(ue[t]);
          float y1 = p1 + bv[1] + bfhi(ue[t]);
          s0 += y0 * __builtin_amdgcn_rcpf(1.f + hw_exp2(y0));
          s1 += y1 * __builtin_amdgcn_rcpf(1.f + hw_exp2(y1));
        }
      }
    };

    load4(ub0, ue0, s);
    int j = s;
    for (; j + 4 < e; j += 8) {
      load4(ub1, ue1, j + 4);
      consume4(ub0, ue0, j);
      if (j + 8 < e) load4(ub0, ue0, j + 8);
      consume4(ub1, ue1, j + 4);
    }
    if (j < e) consume4(ub0, ue0, j);
  }

  s0 *= NEG_LN2;
  s1 *= NEG_LN2;
  unsigned pk = ((unsigned)(unsigned short)f2bf(s1) << 16) | (unsigned short)f2bf(s0);
  *(unsigned*)&Sb[(size_t)n * 128 + d2] = pk;
}

// ---------------- mean pool (batch_ids sorted): wave per 64 nodes, bf16 h ----------------
__global__ void k_pool(const short* __restrict__ hb, const int* __restrict__ batch_ids,
                       float* __restrict__ pooled, float* __restrict__ counts, int N) {
  int lane = threadIdx.x & 63;
  int base = blockIdx.x * 64;
  float acc = 0.f;
  int   cnt = 0;
  int  gcur = -1;
  for (int n = 0; n < 64; ++n) {
    int node = base + n;
    if (node >= N) break;
    int g = batch_ids[node];
    if (g != gcur) {
      if (gcur >= 0) {
        atomicAdd(&pooled[gcur * NODE_DIM + lane], acc);
        if (lane == 0) atomicAdd(&counts[gcur], (float)cnt);
      }
      gcur = g; acc = 0.f; cnt = 0;
    }
    acc += bf2f(hb[(size_t)node * NODE_DIM + lane]);
    cnt++;
  }
  if (gcur >= 0) {
    atomicAdd(&pooled[gcur * NODE_DIM + lane], acc);
    if (lane == 0) atomicAdd(&counts[gcur], (float)cnt);
  }
}

// final linear: un-permute fc_w (pooled is idx64-permuted)
__global__ void k_final(const float* __restrict__ pooled, const float* __restrict__ counts,
                        const float* __restrict__ fc_w, const float* __restrict__ fc_b,
                        float* __restrict__ out, int G) {
  int g = blockIdx.x * blockDim.x + threadIdx.x;
  if (g < G) {
    float acc = 0.f;
    for (int d = 0; d < NODE_DIM; ++d) {
      int col = (d & 3) * 16 + (d >> 2);      // inverse idx64
      acc += pooled[g * NODE_DIM + d] * fc_w[col];
    }
    float c = counts[g];
    if (c < 1.f) c = 1.f;
    out[g] = acc / c + fc_b[0];
  }
}

extern "C" void kernel_launch(void* const* d_in, const int* in_sizes, int n_in,
                              void* d_out, int out_size, void* d_ws, size_t ws_size,
                              hipStream_t stream) {
  const int*   atoms   = (const int*)  d_in[0];
  const int*   eidx    = (const int*)  d_in[1];
  const float* coords  = (const float*)d_in[2];
  const int*   isr     = (const int*)  d_in[3];
  const int*   batch   = (const int*)  d_in[4];
  const float* embed_w = (const float*)d_in[5];
  const float* sub_w   = (const float*)d_in[6];
  const float* W1      = (const float*)d_in[7];
  const float* b1      = (const float*)d_in[8];
  const float* W2      = (const float*)d_in[9];
  const float* b2      = (const float*)d_in[10];
  const float* fc_w    = (const float*)d_in[11];
  const float* fc_b    = (const float*)d_in[12];
  float* out = (float*)d_out;

  const int N = in_sizes[0];
  const int E = in_sizes[1] / 2;
  const int L = in_sizes[8] / HIDDEN;
  const int G = out_size;

  const int* srcv = eidx;
  const int* dstv = eidx + E;

  size_t off = 0;
  auto carve = [&](size_t bytes) -> char* {
    char* p = (char*)d_ws + off;
    off += (bytes + 255) & ~(size_t)255;
    return p;
  };
  short* hb       = (short*)carve((size_t)N * NODE_DIM * 2);
  short* Sb       = (short*)carve((size_t)N * HIDDEN * 2);
  unsigned char* pa = (unsigned char*)carve((size_t)N * HIDDEN);   // fp8 e4m3
  unsigned char* pb = (unsigned char*)carve((size_t)N * HIDDEN);   // fp8 e4m3
  int*   rec      = (int*)  carve((size_t)E * 4);
  int*   sd_p     = (int*)  carve((size_t)E * 4);
  int*   tmp_rec  = (int*)  carve((size_t)E * 4);
  unsigned short* tmp_dl = (unsigned short*)carve((size_t)E * 2);
  int*   cnts     = (int*)  carve((size_t)N * 4);
  int*   colptr   = (int*)  carve(((size_t)N + 2) * 4);
  int*   bkt_total  = (int*)carve((size_t)NBKT_MAX * 4);
  int*   bkt_base   = (int*)carve((size_t)(NBKT_MAX + 1) * 4);
  int*   bkt_cursor = (int*)carve((size_t)NBKT_MAX * 4);
  short* W1abp    = (short*)carve((size_t)L * L1ABSZ * 2);
  short* W2p      = (short*)carve((size_t)L * L2SZ * 2);
  short* tbl      = (short*)carve((size_t)L * TBLSZ * 2);
  float* pooled   = (float*)carve((size_t)G * NODE_DIM * 4);
  float* cntg     = (float*)carve((size_t)G * 4);

  const int nbkt = (N + BKT_SZ - 1) / BKT_SZ;

  k_zero_i<<<(NBKT_MAX + 255) / 256, 256, 0, stream>>>(bkt_total, NBKT_MAX);
  k_init<<<1024, 256, 0, stream>>>(atoms, embed_w, hb, N * NODE_DIM);
  k_edge_pre<<<512, 256, 0, stream>>>(srcv, dstv, coords, isr, rec, bkt_total, E);
  k_zero_f<<<(G * NODE_DIM + G + 255) / 256, 256, 0, stream>>>(pooled, G * NODE_DIM + G);
  k_scan_buckets<<<1, NBKT_MAX, 0, stream>>>(bkt_total, bkt_base, bkt_cursor);
  k_passA<<<256, 256, 0, stream>>>(dstv, rec, bkt_cursor, tmp_rec, tmp_dl, E);
  k_passB<<<nbkt, 256, 0, stream>>>(tmp_rec, tmp_dl, bkt_base, sd_p, colptr, cnts, N, E, nbkt);
  k_pack_w1ab<<<(L * L1ABSZ + 255) / 256, 256, 0, stream>>>(W1, W1abp, L * L1ABSZ);
  k_pack_w2<<<(L * L2SZ + 255) / 256, 256, 0, stream>>>(W2, W2p, L * L2SZ);
  k_tbl<<<(L * 2 * TBL_BINS * 128 + 255) / 256, 256, 0, stream>>>(W1, sub_w, tbl,
                                                                  L * 2 * TBL_BINS * 128);

  const int nblk_n = (N + 63) / 64;
  const int nblk_g = (N + 3) / 4;
  for (int l = 0; l < L; ++l) {
    k_node<<<nblk_n, 256, 0, stream>>>(
        hb, Sb, cnts,
        (l > 0) ? W2p + (size_t)(l - 1) * L2SZ : (const short*)nullptr,
        (l > 0) ? b2 + (size_t)(l - 1) * NODE_DIM : (const float*)nullptr,
        W1abp + (size_t)l * L1ABSZ, b1 + (size_t)l * HIDDEN,
        pa, pb, N);
    k_gather<<<nblk_g, 256, 0, stream>>>(pa, pb, tbl + (size_t)l * TBLSZ,
                                         sd_p, colptr, Sb, N);
  }
  k_node<<<nblk_n, 256, 0, stream>>>(
      hb, Sb, cnts,
      W2p + (size_t)(L - 1) * L2SZ, b2 + (size_t)(L - 1) * NODE_DIM,
      (const short*)nullptr, (const float*)nullptr, pa, pb, N);

  k_pool<<<(N + 63) / 64, 64, 0, stream>>>(hb, batch, pooled, cntg, N);
  k_final<<<1, 64, 0, stream>>>(pooled, cntg, fc_w, fc_b, out, G);
}

// Round 13
// 501.331 us; speedup vs baseline: 1.0824x; 1.0281x over previous
//
#include <hip/hip_runtime.h>
#include <hip/hip_bf16.h>
#include <math.h>

#define NODE_DIM  64
#define EDGE_DIM  32
#define NUM_GAUSS 16
#define HIDDEN    128
#define CAT_DIM   160
#define TBL_BINS  2048
#define TBL_SCALE 256.0f                // bins per unit distance (domain [0,8))
#define L1ABSZ    (64 * 256)            // packed W1ab per layer (K=64, N=256)
#define L2SZ      (HIDDEN * NODE_DIM)   // packed W2 per layer   (K=128, N=64)
#define TBLSZ     (2 * TBL_BINS * 128)  // per-layer edge-attr table entries

// Pre-scale: pa/pb/tbl carry value * -log2(e); gather uses exp2 directly and
// un-scales the accumulated sum by -ln(2) once per node.
#define NEG_L2E   (-1.442695040888963f)
#define NEG_LN2   (-0.6931471805599453f)

// CSR build buckets: 512 nodes per bucket, max 1024 buckets (N <= 524288)
#define BKT_SH    9
#define BKT_SZ    512
#define NBKT_MAX  1024

// Column-permuted storage: idx64(c)=(c&15)*4+(c>>4)  (64-wide: hb, ht)
//                          idx128(c)=(c&15)*8+(c>>4) (128-wide: pa, pb, tbl, Sb)
// Weights' K dims are packed with the same permutation, so all GEMMs are invariant.
// Edge record: rec = (src << 12) | ety   (src<2^20, ety<2^12) — single 4 B scatter.
// h is carried in bf16 only (hb).
// pa AND pb (the gathered message halves) are stored FP8 e4m3 (128 B rows) to halve
// the gather-path traffic; tbl and Sb stay bf16.

typedef __attribute__((ext_vector_type(8))) short short8;
typedef __attribute__((ext_vector_type(4))) short short4v;
typedef __attribute__((ext_vector_type(4))) float float4v;
typedef __attribute__((ext_vector_type(2))) float floatx2;

static __device__ __forceinline__ short f2bf(float x) {
  __hip_bfloat16 h = __float2bfloat16(x);
  return *reinterpret_cast<short*>(&h);
}
static __device__ __forceinline__ float bf2f(short s) {
  return __uint_as_float(((unsigned)(unsigned short)s) << 16);
}
static __device__ __forceinline__ float bflo(unsigned u) { return __uint_as_float(u << 16); }
static __device__ __forceinline__ float bfhi(unsigned u) { return __uint_as_float(u & 0xffff0000u); }

// Bare HW exp2: single v_exp_f32 (VOP1). Bypasses any OCML wrapper the libm
// exp2f path might pull in; VALU->VALU dependencies are HW-interlocked.
static __device__ __forceinline__ float hw_exp2(float x) {
  float r;
  asm("v_exp_f32 %0, %1" : "=v"(r) : "v"(x));
  return r;
}

// ---------------- init: hb (idx64-permuted) = embed[atoms] ----------------
__global__ void k_init(const int* __restrict__ atoms, const float* __restrict__ embed_w,
                       short* __restrict__ hb, int n) {
  int stride = gridDim.x * blockDim.x;
  for (int i = blockIdx.x * blockDim.x + threadIdx.x; i < n; i += stride) {
    int p = i & 63;
    int col = (p & 3) * 16 + (p >> 2);          // inverse idx64
    hb[i] = f2bf(embed_w[atoms[i >> 6] * NODE_DIM + col]);
  }
}

__global__ void k_zero_f(float* __restrict__ p, int n) {
  int stride = gridDim.x * blockDim.x;
  for (int i = blockIdx.x * blockDim.x + threadIdx.x; i < n; i += stride) p[i] = 0.f;
}
__global__ void k_zero_i(int* __restrict__ p, int n) {
  int i = blockIdx.x * blockDim.x + threadIdx.x;
  if (i < n) p[i] = 0;
}

// ---------------- edge precompute: rec = (src<<12)|(kind<<11)|bin; LDS bucket histogram ----------------
__global__ __launch_bounds__(256) void k_edge_pre(
    const int* __restrict__ src, const int* __restrict__ dst,
    const float* __restrict__ coords, const int* __restrict__ isr,
    int* __restrict__ rec, int* __restrict__ bkt_total, int E) {
  __shared__ int h[NBKT_MAX];
  for (int i = threadIdx.x; i < NBKT_MAX; i += 256) h[i] = 0;
  __syncthreads();
  int stride = gridDim.x * blockDim.x;
  for (int e = blockIdx.x * blockDim.x + threadIdx.x; e < E; e += stride) {
    int s = src[e], d = dst[e];
    float dx = coords[s*3+0] - coords[d*3+0];
    float dy = coords[s*3+1] - coords[d*3+1];
    float dz = coords[s*3+2] - coords[d*3+2];
    float dist = sqrtf(dx*dx + dy*dy + dz*dz);
    int bin = (int)(dist * TBL_SCALE);
    bin = (bin > TBL_BINS - 1) ? TBL_BINS - 1 : bin;
    int kind = (isr[s] != isr[d]) ? 1 : 0;
    rec[e] = (s << 12) | (kind << 11) | bin;
    atomicAdd(&h[d >> BKT_SH], 1);
  }
  __syncthreads();
  for (int i = threadIdx.x; i < NBKT_MAX; i += 256)
    if (h[i]) atomicAdd(&bkt_total[i], h[i]);
}

// ---------------- bucket exclusive scan (single block, 1024 threads) ----------------
__global__ void k_scan_buckets(const int* __restrict__ tot, int* __restrict__ base,
                               int* __restrict__ cur) {
  __shared__ int s[NBKT_MAX];
  int t = threadIdx.x;
  int v = tot[t];
  s[t] = v;
  __syncthreads();
  for (int o = 1; o < NBKT_MAX; o <<= 1) {
    int u = (t >= o) ? s[t - o] : 0;
    __syncthreads();
    s[t] += u;
    __syncthreads();
  }
  int ex = s[t] - v;
  base[t] = ex;
  cur[t]  = ex;
}

// ---------------- pass A: bucket-group records; per-(block,bucket) contiguous segments ----------------
__global__ __launch_bounds__(256) void k_passA(
    const int* __restrict__ dst, const int* __restrict__ rec,
    int* __restrict__ bkt_cursor,
    int* __restrict__ tmp_rec, unsigned short* __restrict__ tmp_dl, int E) {
  __shared__ int h[NBKT_MAX];
  __shared__ int c[NBKT_MAX];
  const int tid = threadIdx.x;
  const int chunk = (E + gridDim.x - 1) / gridDim.x;
  const int c0 = blockIdx.x * chunk;
  const int c1 = (c0 + chunk < E) ? c0 + chunk : E;
  for (int i = tid; i < NBKT_MAX; i += 256) h[i] = 0;
  __syncthreads();
  for (int e = c0 + tid; e < c1; e += 256)
    atomicAdd(&h[dst[e] >> BKT_SH], 1);
  __syncthreads();
  for (int i = tid; i < NBKT_MAX; i += 256)
    c[i] = h[i] ? atomicAdd(&bkt_cursor[i], h[i]) : 0;
  __syncthreads();
  for (int e = c0 + tid; e < c1; e += 256) {
    int d = dst[e];
    int p = atomicAdd(&c[d >> BKT_SH], 1);
    tmp_rec[p] = rec[e];
    tmp_dl[p]  = (unsigned short)(d & (BKT_SZ - 1));
  }
}

// ---------------- pass B: per-bucket counting sort by local dst; emits sd_p, colptr, cnts ----------------
__global__ __launch_bounds__(256) void k_passB(
    const int* __restrict__ tmp_rec, const unsigned short* __restrict__ tmp_dl,
    const int* __restrict__ bkt_base,
    int* __restrict__ sd_p, int* __restrict__ colptr, int* __restrict__ cnts,
    int N, int E, int nbkt) {
  __shared__ int h[BKT_SZ];
  __shared__ int cur[BKT_SZ];
  __shared__ int ps[256];
  const int tid = threadIdx.x;
  const int b = blockIdx.x;
  const int rb = bkt_base[b];
  const int re = (b == nbkt - 1) ? E : bkt_base[b + 1];

  h[tid] = 0; h[tid + 256] = 0;
  __syncthreads();
  for (int r = rb + tid; r < re; r += 256)
    atomicAdd(&h[tmp_dl[r]], 1);
  __syncthreads();

  // exclusive scan over 512 counts: pairwise + Hillis-Steele over 256 partials
  int a0 = h[2*tid], a1 = h[2*tid + 1];
  ps[tid] = a0 + a1;
  __syncthreads();
  for (int o = 1; o < 256; o <<= 1) {
    int u = (tid >= o) ? ps[tid - o] : 0;
    __syncthreads();
    ps[tid] += u;
    __syncthreads();
  }
  int e0 = tid ? ps[tid - 1] : 0;
  int g0 = rb + e0;
  int g1 = g0 + a0;
  cur[2*tid]     = g0;
  cur[2*tid + 1] = g1;
  int node0 = b * BKT_SZ + 2*tid;
  if (node0 < N)     { colptr[node0]     = g0; cnts[node0]     = a0; }
  if (node0 + 1 < N) { colptr[node0 + 1] = g1; cnts[node0 + 1] = a1; }
  if (b == 0 && tid == 0) colptr[N] = E;
  __syncthreads();

  for (int r = rb + tid; r < re; r += 256) {
    int dl = tmp_dl[r];
    int p = atomicAdd(&cur[dl], 1);
    sd_p[p] = tmp_rec[r];
  }
}

// ---------------- edge-attr table: thread per OUTPUT ELEMENT (2M threads) ----------------
__global__ void k_tbl(const float* __restrict__ W1, const float* __restrict__ sub_w,
                      short* __restrict__ tbl, int total) {
  int i = blockIdx.x * 256 + threadIdx.x;     // i over [0, L*2*TBL_BINS*128)
  if (i >= total) return;
  int col  = i & 127;
  int idx  = i >> 7;                           // (l, kind, bin)
  int bin  = idx & (TBL_BINS - 1);
  int kind = (idx >> 11) & 1;
  int l    = idx >> 12;
  float dist = ((float)bin + 0.5f) * (1.0f / TBL_SCALE);
  const float* W1c = W1 + (size_t)l * CAT_DIM * HIDDEN + 128 * HIDDEN;
  float acc = 0.f;
  #pragma unroll
  for (int g = 0; g < 16; ++g) {
    float t = dist - (float)g * (1.0f / 3.0f);
    acc += __expf(-4.5f * t * t) * W1c[g * 128 + col];
  }
  #pragma unroll
  for (int g = 0; g < 16; ++g)
    acc += sub_w[kind * 16 + g] * W1c[(16 + g) * 128 + col];
  tbl[(size_t)idx * 128 + (col & 15) * 8 + (col >> 4)] = f2bf(acc * NEG_L2E);   // idx128, pre-scaled
}

// ---------------- weight packing: B-frag order, K permuted to match storage ----------------
__global__ void k_pack_w1ab(const float* __restrict__ W1, short* __restrict__ Wp, int total) {
  int i = blockIdx.x * blockDim.x + threadIdx.x;
  if (i >= total) return;
  int l = i / L1ABSZ, r = i % L1ABSZ;
  int k = r / 256, n = r % 256;                 // k = original h col (0..63)
  int kp = (k & 15) * 4 + (k >> 4);             // idx64
  int kt = kp >> 5, quad = (kp >> 3) & 3, j = kp & 7;
  int srow = (n < 128) ? k : 64 + k;
  int scol = (n < 128) ? n : n - 128;
  Wp[l * L1ABSZ + ((kt*4 + quad) * 256 + n) * 8 + j] =
      f2bf(W1[(size_t)l * CAT_DIM * HIDDEN + srow * HIDDEN + scol] * NEG_L2E);  // pre-scaled
}
__global__ void k_pack_w2(const float* __restrict__ W, short* __restrict__ Wp, int total) {
  int i = blockIdx.x * blockDim.x + threadIdx.x;
  if (i >= total) return;
  int l = i / L2SZ, r = i % L2SZ;
  int k = r / NODE_DIM, n = r % NODE_DIM;       // k = original hidden col (0..127)
  int kp = (k & 15) * 8 + (k >> 4);             // idx128
  int kt = kp >> 5, quad = (kp >> 3) & 3, j = kp & 7;
  Wp[l * L2SZ + ((kt*4 + quad) * NODE_DIM + n) * 8 + j] = f2bf(W[i]);
}

// ---------------- node kernel: [agg=Sb@W2+cnt*b2; h=relu(h+agg)] ; [pa|pb = h@W1ab -> fp8] ----------------
__global__ __launch_bounds__(256, 4) void k_node(
    short* __restrict__ hb,
    const short* __restrict__ Sb, const int* __restrict__ cnts,
    const short* __restrict__ W2p, const float* __restrict__ b2,
    const short* __restrict__ W1abp, const float* __restrict__ b1,
    unsigned char* __restrict__ pa, unsigned char* __restrict__ pb, int N)
{
  __shared__ short ht[64 * 72];

  const int tid  = threadIdx.x;
  const int lane = tid & 63;
  const int w    = tid >> 6;
  const int quad = lane >> 4;
  const int l16  = lane & 15;
  const int base = blockIdx.x * 64 + w * 16;

  if (W2p) {
    float4v acc[4];
    #pragma unroll
    for (int nt = 0; nt < 4; ++nt) acc[nt] = (float4v)0.f;
    const int arow = base + l16;
    const bool av = arow < N;
    #pragma unroll
    for (int kt = 0; kt < 4; ++kt) {
      short8 a = av ? *(const short8*)&Sb[(size_t)arow * 128 + kt*32 + quad*8]
                    : (short8)0;
      #pragma unroll
      for (int nt = 0; nt < 4; ++nt) {
        short8 b = *(const short8*)&W2p[((kt*4 + quad) * NODE_DIM + nt*16 + l16) * 8];
        acc[nt] = __builtin_amdgcn_mfma_f32_16x16x32_bf16(a, b, acc[nt], 0, 0, 0);
      }
    }
    float bb[4];
    #pragma unroll
    for (int nt = 0; nt < 4; ++nt) bb[nt] = b2[nt*16 + l16];
    #pragma unroll
    for (int r = 0; r < 4; ++r) {
      int row  = base + quad*4 + r;
      int lrow = w*16 + quad*4 + r;
      if (row < N) {
        float cf = (float)cnts[row];
        short4v hv = *(const short4v*)&hb[(size_t)row * 64 + l16*4];  // permuted pos l16*4+nt
        float v0 = fmaxf(bf2f(hv[0]) + acc[0][r] + cf * bb[0], 0.f);
        float v1 = fmaxf(bf2f(hv[1]) + acc[1][r] + cf * bb[1], 0.f);
        float v2 = fmaxf(bf2f(hv[2]) + acc[2][r] + cf * bb[2], 0.f);
        float v3 = fmaxf(bf2f(hv[3]) + acc[3][r] + cf * bb[3], 0.f);
        short4v hs = {f2bf(v0), f2bf(v1), f2bf(v2), f2bf(v3)};
        *(short4v*)&hb[(size_t)row * 64 + l16*4] = hs;
        *(short4v*)&ht[lrow * 72 + l16*4] = hs;
      } else {
        *(short4v*)&ht[lrow * 72 + l16*4] = (short4v)0;
      }
    }
  } else {
    int row = base + l16;
    #pragma unroll
    for (int c = 0; c < 2; ++c) {
      int colc = quad*16 + c*8;
      short8 v = (row < N) ? *(const short8*)&hb[(size_t)row * 64 + colc] : (short8)0;
      *(short8*)&ht[(w*16 + l16) * 72 + colc] = v;
    }
  }

  if (W1abp) {
    float4v acc[16];
    #pragma unroll
    for (int nt = 0; nt < 16; ++nt) acc[nt] = (float4v)0.f;
    #pragma unroll
    for (int kt = 0; kt < 2; ++kt) {
      short8 a = *(const short8*)&ht[(w*16 + l16) * 72 + kt*32 + quad*8];
      #pragma unroll
      for (int nt = 0; nt < 16; ++nt) {
        short8 b = *(const short8*)&W1abp[((kt*4 + quad) * 256 + nt*16 + l16) * 8];
        acc[nt] = __builtin_amdgcn_mfma_f32_16x16x32_bf16(a, b, acc[nt], 0, 0, 0);
      }
    }
    float b1a[8];
    #pragma unroll
    for (int nt = 0; nt < 8; ++nt) b1a[nt] = b1[nt*16 + l16] * NEG_L2E;  // pre-scaled bias
    #pragma unroll
    for (int r = 0; r < 4; ++r) {
      int row = base + quad*4 + r;
      if (row < N) {
        // pa half -> fp8 e4m3 (HW pack, RNE): byte k = permuted col l16*8+k
        int a0 = 0, a1 = 0;
        a0 = __builtin_amdgcn_cvt_pk_fp8_f32(acc[0][r] + b1a[0], acc[1][r] + b1a[1], a0, false);
        a0 = __builtin_amdgcn_cvt_pk_fp8_f32(acc[2][r] + b1a[2], acc[3][r] + b1a[3], a0, true);
        a1 = __builtin_amdgcn_cvt_pk_fp8_f32(acc[4][r] + b1a[4], acc[5][r] + b1a[5], a1, false);
        a1 = __builtin_amdgcn_cvt_pk_fp8_f32(acc[6][r] + b1a[6], acc[7][r] + b1a[7], a1, true);
        uint2 pka; pka.x = (unsigned)a0; pka.y = (unsigned)a1;
        *(uint2*)&pa[(size_t)row * 128 + l16*8] = pka;
        // pb half -> fp8 e4m3
        int w0 = 0, w1 = 0;
        w0 = __builtin_amdgcn_cvt_pk_fp8_f32(acc[8][r],  acc[9][r],  w0, false);
        w0 = __builtin_amdgcn_cvt_pk_fp8_f32(acc[10][r], acc[11][r], w0, true);
        w1 = __builtin_amdgcn_cvt_pk_fp8_f32(acc[12][r], acc[13][r], w1, false);
        w1 = __builtin_amdgcn_cvt_pk_fp8_f32(acc[14][r], acc[15][r], w1, true);
        uint2 pk8; pk8.x = (unsigned)w0; pk8.y = (unsigned)w1;
        *(uint2*)&pb[(size_t)row * 128 + l16*8] = pk8;
      }
    }
  }
}

// ---------------- gather kernel: wave per node, scalar record stream, fp8 pa/pb rows ----------------
__global__ __launch_bounds__(256, 8) void k_gather(
    const unsigned char* __restrict__ pa, const unsigned char* __restrict__ pb,
    const short* __restrict__ tblL,
    const int* __restrict__ sd_p, const int* __restrict__ colptr,
    short* __restrict__ Sb, int N)
{
  int n = blockIdx.x * 4 + (threadIdx.x >> 6);
  if (n >= N) return;
  const int lane = threadIdx.x & 63;
  const int d2 = lane * 2;                 // byte offset in 128 B fp8 row / short idx in Sb
  const int d4 = lane * 4;                 // byte offset within a 256 B bf16 row

  // wave-uniform edge range -> scalar (SALU) bounds, uniform branches
  const int s = __builtin_amdgcn_readfirstlane(colptr[n]);
  const int e = __builtin_amdgcn_readfirstlane(colptr[n + 1]);

  unsigned short upa = *(const unsigned short*)&pa[(size_t)n * 128 + d2];
  floatx2 pv = __builtin_amdgcn_cvt_pk_f32_fp8((int)upa, false);
  const float p0 = pv[0], p1 = pv[1];      // pre-scaled: p = -log2e * (h@W1a + b1)
  float s0 = 0.f, s1 = 0.f;

  const char* pbB = (const char*)pb;
  const char* tbB = (const char*)tblL;

  if (e > s) {
    unsigned short ub0[4], ub1[4];
    unsigned ue0[4], ue1[4];

    auto load4 = [&](unsigned short (&ub)[4], unsigned (&ue)[4], int j) {
      #pragma unroll
      for (int t = 0; t < 4; ++t) {
        int jj = (j + t < e) ? j + t : s;       // scalar clamp: always a valid record
        int rc = __builtin_amdgcn_readfirstlane(sd_p[jj]);  // wave-uniform record
        // scalar row bases + per-lane offset -> global_load v, v_off, s[base]
        const char* pr = pbB + ((size_t)((unsigned)rc >> 12) << 7);   // 128 B fp8 rows
        const char* tr = tbB + ((size_t)(rc & 0xfff) << 8);           // 256 B bf16 rows
        ub[t] = *(const unsigned short*)(pr + d2);
        ue[t] = *(const unsigned*)(tr + d4);
      }
    };
    // y = -x*log2e (all inputs pre-scaled); exp2(y)=e^-x; acc += y/(1+e^-x);
    // final un-scale by -ln2 recovers sum of x*sigmoid(x).
    auto consume4 = [&](unsigned short (&ub)[4], unsigned (&ue)[4], int j) {
      #pragma unroll
      for (int t = 0; t < 4; ++t) {
        if (j + t < e) {                        // wave-uniform branch
          floatx2 bv = __builtin_amdgcn_cvt_pk_f32_fp8((int)ub[t], false);  // 2 fp8 -> 2 f32
          float y0 = p0 + bv[0] + bflo(ue[t]);
          float y1 = p1 + bv[1] + bfhi(ue[t]);
          s0 += y0 * __builtin_amdgcn_rcpf(1.f + hw_exp2(y0));
          s1 += y1 * __builtin_amdgcn_rcpf(1.f + hw_exp2(y1));
        }
      }
    };

    load4(ub0, ue0, s);
    int j = s;
    for (; j + 4 < e; j += 8) {
      load4(ub1, ue1, j + 4);
      consume4(ub0, ue0, j);
      if (j + 8 < e) load4(ub0, ue0, j + 8);
      consume4(ub1, ue1, j + 4);
    }
    if (j < e) consume4(ub0, ue0, j);
  }

  s0 *= NEG_LN2;
  s1 *= NEG_LN2;
  unsigned pk = ((unsigned)(unsigned short)f2bf(s1) << 16) | (unsigned short)f2bf(s0);
  *(unsigned*)&Sb[(size_t)n * 128 + d2] = pk;
}

// ---------------- mean pool (batch_ids sorted): wave per 64 nodes, bf16 h ----------------
__global__ void k_pool(const short* __restrict__ hb, const int* __restrict__ batch_ids,
                       float* __restrict__ pooled, float* __restrict__ counts, int N) {
  int lane = threadIdx.x & 63;
  int base = blockIdx.x * 64;
  float acc = 0.f;
  int   cnt = 0;
  int  gcur = -1;
  for (int n = 0; n < 64; ++n) {
    int node = base + n;
    if (node >= N) break;
    int g = batch_ids[node];
    if (g != gcur) {
      if (gcur >= 0) {
        atomicAdd(&pooled[gcur * NODE_DIM + lane], acc);
        if (lane == 0) atomicAdd(&counts[gcur], (float)cnt);
      }
      gcur = g; acc = 0.f; cnt = 0;
    }
    acc += bf2f(hb[(size_t)node * NODE_DIM + lane]);
    cnt++;
  }
  if (gcur >= 0) {
    atomicAdd(&pooled[gcur * NODE_DIM + lane], acc);
    if (lane == 0) atomicAdd(&counts[gcur], (float)cnt);
  }
}

// final linear: un-permute fc_w (pooled is idx64-permuted)
__global__ void k_final(const float* __restrict__ pooled, const float* __restrict__ counts,
                        const float* __restrict__ fc_w, const float* __restrict__ fc_b,
                        float* __restrict__ out, int G) {
  int g = blockIdx.x * blockDim.x + threadIdx.x;
  if (g < G) {
    float acc = 0.f;
    for (int d = 0; d < NODE_DIM; ++d) {
      int col = (d & 3) * 16 + (d >> 2);      // inverse idx64
      acc += pooled[g * NODE_DIM + d] * fc_w[col];
    }
    float c = counts[g];
    if (c < 1.f) c = 1.f;
    out[g] = acc / c + fc_b[0];
  }
}

extern "C" void kernel_launch(void* const* d_in, const int* in_sizes, int n_in,
                              void* d_out, int out_size, void* d_ws, size_t ws_size,
                              hipStream_t stream) {
  const int*   atoms   = (const int*)  d_in[0];
  const int*   eidx    = (const int*)  d_in[1];
  const float* coords  = (const float*)d_in[2];
  const int*   isr     = (const int*)  d_in[3];
  const int*   batch   = (const int*)  d_in[4];
  const float* embed_w = (const float*)d_in[5];
  const float* sub_w   = (const float*)d_in[6];
  const float* W1      = (const float*)d_in[7];
  const float* b1      = (const float*)d_in[8];
  const float* W2      = (const float*)d_in[9];
  const float* b2      = (const float*)d_in[10];
  const float* fc_w    = (const float*)d_in[11];
  const float* fc_b    = (const float*)d_in[12];
  float* out = (float*)d_out;

  const int N = in_sizes[0];
  const int E = in_sizes[1] / 2;
  const int L = in_sizes[8] / HIDDEN;
  const int G = out_size;

  const int* srcv = eidx;
  const int* dstv = eidx + E;

  size_t off = 0;
  auto carve = [&](size_t bytes) -> char* {
    char* p = (char*)d_ws + off;
    off += (bytes + 255) & ~(size_t)255;
    return p;
  };
  short* hb       = (short*)carve((size_t)N * NODE_DIM * 2);
  short* Sb       = (short*)carve((size_t)N * HIDDEN * 2);
  unsigned char* pa = (unsigned char*)carve((size_t)N * HIDDEN);   // fp8 e4m3
  unsigned char* pb = (unsigned char*)carve((size_t)N * HIDDEN);   // fp8 e4m3
  int*   rec      = (int*)  carve((size_t)E * 4);
  int*   sd_p     = (int*)  carve((size_t)E * 4);
  int*   tmp_rec  = (int*)  carve((size_t)E * 4);
  unsigned short* tmp_dl = (unsigned short*)carve((size_t)E * 2);
  int*   cnts     = (int*)  carve((size_t)N * 4);
  int*   colptr   = (int*)  carve(((size_t)N + 2) * 4);
  int*   bkt_total  = (int*)carve((size_t)NBKT_MAX * 4);
  int*   bkt_base   = (int*)carve((size_t)(NBKT_MAX + 1) * 4);
  int*   bkt_cursor = (int*)carve((size_t)NBKT_MAX * 4);
  short* W1abp    = (short*)carve((size_t)L * L1ABSZ * 2);
  short* W2p      = (short*)carve((size_t)L * L2SZ * 2);
  short* tbl      = (short*)carve((size_t)L * TBLSZ * 2);
  float* pooled   = (float*)carve((size_t)G * NODE_DIM * 4);
  float* cntg     = (float*)carve((size_t)G * 4);

  const int nbkt = (N + BKT_SZ - 1) / BKT_SZ;

  k_zero_i<<<(NBKT_MAX + 255) / 256, 256, 0, stream>>>(bkt_total, NBKT_MAX);
  k_init<<<1024, 256, 0, stream>>>(atoms, embed_w, hb, N * NODE_DIM);
  k_edge_pre<<<512, 256, 0, stream>>>(srcv, dstv, coords, isr, rec, bkt_total, E);
  k_zero_f<<<(G * NODE_DIM + G + 255) / 256, 256, 0, stream>>>(pooled, G * NODE_DIM + G);
  k_scan_buckets<<<1, NBKT_MAX, 0, stream>>>(bkt_total, bkt_base, bkt_cursor);
  k_passA<<<256, 256, 0, stream>>>(dstv, rec, bkt_cursor, tmp_rec, tmp_dl, E);
  k_passB<<<nbkt, 256, 0, stream>>>(tmp_rec, tmp_dl, bkt_base, sd_p, colptr, cnts, N, E, nbkt);
  k_pack_w1ab<<<(L * L1ABSZ + 255) / 256, 256, 0, stream>>>(W1, W1abp, L * L1ABSZ);
  k_pack_w2<<<(L * L2SZ + 255) / 256, 256, 0, stream>>>(W2, W2p, L * L2SZ);
  k_tbl<<<(L * 2 * TBL_BINS * 128 + 255) / 256, 256, 0, stream>>>(W1, sub_w, tbl,
                                                                  L * 2 * TBL_BINS * 128);

  const int nblk_n = (N + 63) / 64;
  const int nblk_g = (N + 3) / 4;
  for (int l = 0; l < L; ++l) {
    k_node<<<nblk_n, 256, 0, stream>>>(
        hb, Sb, cnts,
        (l > 0) ? W2p + (size_t)(l - 1) * L2SZ : (const short*)nullptr,
        (l > 0) ? b2 + (size_t)(l - 1) * NODE_DIM : (const float*)nullptr,
        W1abp + (size_t)l * L1ABSZ, b1 + (size_t)l * HIDDEN,
        pa, pb, N);
    k_gather<<<nblk_g, 256, 0, stream>>>(pa, pb, tbl + (size_t)l * TBLSZ,
                                         sd_p, colptr, Sb, N);
  }
  k_node<<<nblk_n, 256, 0, stream>>>(
      hb, Sb, cnts,
      W2p + (size_t)(L - 1) * L2SZ, b2 + (size_t)(L - 1) * NODE_DIM,
      (const short*)nullptr, (const float*)nullptr, pa, pb, N);

  k_pool<<<(N + 63) / 64, 64, 0, stream>>>(hb, batch, pooled, cntg, N);
  k_final<<<1, 64, 0, stream>>>(pooled, cntg, fc_w, fc_b, out, G);
}